// Round 1
// baseline (12730.797 us; speedup 1.0000x reference)
//
#include <hip/hip_runtime.h>

typedef __bf16 bf16;
typedef __bf16 bf16x8 __attribute__((ext_vector_type(8)));
typedef float f32x4 __attribute__((ext_vector_type(4)));

#define M0   120000
#define M0P  120064   // 938*128
#define K0   768
#define HID  512
#define NREL 5
#define N1   30000
#define N1P  30080    // 235*128
#define E0   600000
#define N2   8000
#define N2P  8064     // 63*128
#define E1   150000
#define OUTC 153
#define OUTP 256

#define GLOAD_LDS16(g, s) \
  __builtin_amdgcn_global_load_lds((const __attribute__((address_space(1))) void*)(g), \
                                   (__attribute__((address_space(3))) void*)(s), 16, 0, 0)

// ---------------------------------------------------------------------------
// GEMM: C[M x N] = A[M x K](bf16, row-major) * Bt[N x K](bf16, row-major)^T
// 128x128 tile, 4 waves of 64x64, mfma_f32_16x16x32_bf16, global_load_lds(16B)
// MODE 0: store bf16, ldc=N, no guard. MODE 1: store f32, ldc=N, no guard.
// MODE 2: store f32 + bias, guards row<Mv col<Nv, ldc param.
// ---------------------------------------------------------------------------
template <int MODE>
__global__ __launch_bounds__(256) void gemm_bt(
    const bf16* __restrict__ A, const bf16* __restrict__ Bt, void* __restrict__ Cout,
    int N, int K, int Mv, int Nv, int ldc, const float* __restrict__ bias)
{
  __shared__ __attribute__((aligned(16))) bf16 As[128 * 32];
  __shared__ __attribute__((aligned(16))) bf16 Bs[128 * 32];
  const int tid = threadIdx.x;
  const int w = tid >> 6, l = tid & 63;
  const int tm = blockIdx.x * 128, tn = blockIdx.y * 128;
  const int wm = (w >> 1) * 64, wn = (w & 1) * 64;
  const int lr = l & 15, q = l >> 4;

  f32x4 acc[4][4] = {};

  const int arow = l >> 2;          // staging row within 16-row chunk
  const int acol = (l & 3) * 8;     // staging col (k) offset
  const bf16* Ag = A + (size_t)tm * K + acol;
  const bf16* Bg = Bt + (size_t)tn * K + acol;

  for (int k0 = 0; k0 < K; k0 += 32) {
#pragma unroll
    for (int i = 0; i < 2; i++) {
      int rb = __builtin_amdgcn_readfirstlane(16 * (2 * w + i));
      GLOAD_LDS16(Ag + (size_t)(rb + arow) * K + k0, As + rb * 32);
      GLOAD_LDS16(Bg + (size_t)(rb + arow) * K + k0, Bs + rb * 32);
    }
    __syncthreads();
    bf16x8 af[4], bfr[4];
#pragma unroll
    for (int i = 0; i < 4; i++)
      af[i] = *(const bf16x8*)&As[(wm + i * 16 + lr) * 32 + q * 8];
#pragma unroll
    for (int jj = 0; jj < 4; jj++)
      bfr[jj] = *(const bf16x8*)&Bs[(wn + jj * 16 + lr) * 32 + q * 8];
#pragma unroll
    for (int i = 0; i < 4; i++)
#pragma unroll
      for (int jj = 0; jj < 4; jj++)
        acc[i][jj] = __builtin_amdgcn_mfma_f32_16x16x32_bf16(af[i], bfr[jj], acc[i][jj], 0, 0, 0);
    __syncthreads();
  }

  // C/D layout (m89-verified): col = lane&15, row = (lane>>4)*4 + reg
#pragma unroll
  for (int i = 0; i < 4; i++)
#pragma unroll
    for (int jj = 0; jj < 4; jj++)
#pragma unroll
      for (int r = 0; r < 4; r++) {
        int row = tm + wm + i * 16 + q * 4 + r;
        int col = tn + wn + jj * 16 + lr;
        float v = acc[i][jj][r];
        if (MODE == 0) {
          ((bf16*)Cout)[(size_t)row * N + col] = (bf16)v;
        } else if (MODE == 1) {
          ((float*)Cout)[(size_t)row * N + col] = v;
        } else {
          if (row < Mv && col < Nv)
            ((float*)Cout)[(size_t)row * ldc + col] = v + bias[col];
        }
      }
}

// ---------------------------------------------------------------------------
// fp32 -> bf16 cast with zero padding beyond nvalid
// ---------------------------------------------------------------------------
__global__ void cast_pad_k(const float* __restrict__ src, bf16* __restrict__ dst,
                           long nvalid, long ntot)
{
  long i = ((long)blockIdx.x * 256 + threadIdx.x) * 8;
  if (i >= ntot) return;
  bf16x8 o;
  if (i + 8 <= nvalid) {
    float4 v0 = *(const float4*)(src + i);
    float4 v1 = *(const float4*)(src + i + 4);
    o[0] = (bf16)v0.x; o[1] = (bf16)v0.y; o[2] = (bf16)v0.z; o[3] = (bf16)v0.w;
    o[4] = (bf16)v1.x; o[5] = (bf16)v1.y; o[6] = (bf16)v1.z; o[7] = (bf16)v1.w;
  } else {
#pragma unroll
    for (int t = 0; t < 8; t++)
      o[t] = (i + t < nvalid) ? (bf16)src[i + t] : (bf16)0.f;
  }
  *(bf16x8*)(dst + i) = o;
}

// W[K x Nsrc] fp32 -> Wt[Ndst x K] bf16 (rows n >= Nvalid zeroed). grid=(K/256, Ndst)
__global__ void transpose_cast_k(const float* __restrict__ W, bf16* __restrict__ Wt,
                                 int K, int Nsrc, int Nvalid)
{
  int n = blockIdx.y;
  int k = blockIdx.x * 256 + threadIdx.x;
  Wt[(size_t)n * K + k] = (n < Nvalid) ? (bf16)W[(size_t)k * Nsrc + n] : (bf16)0.f;
}

// ---------------------------------------------------------------------------
// attention score projections: a_s[n][h] = <h_row[h*128:...], asj[h]>, same a_d
// grid = Msrc blocks x 64 threads
// ---------------------------------------------------------------------------
__global__ void scores_k(const bf16* __restrict__ h, const float* __restrict__ asj,
                         const float* __restrict__ adj, float* __restrict__ as_out,
                         float* __restrict__ ad_out, int ndst)
{
  int n = blockIdx.x;
  int l = threadIdx.x;
  const bf16x8 hv = *(const bf16x8*)(h + (size_t)n * HID + l * 8);
  int head = l >> 4;
  int base = head * 128 + (l & 15) * 8;
  float ps = 0.f, pd = 0.f;
#pragma unroll
  for (int t = 0; t < 8; t++) {
    float hx = (float)hv[t];
    ps += hx * asj[base + t];
    pd += hx * adj[base + t];
  }
#pragma unroll
  for (int o = 8; o > 0; o >>= 1) {
    ps += __shfl_down(ps, o, 16);
    pd += __shfl_down(pd, o, 16);
  }
  if ((l & 15) == 0) {
    as_out[n * 4 + head] = ps;
    if (n < ndst) ad_out[n * 4 + head] = pd;
  }
}

// monotone float<->uint mapping for atomicMax on signed floats
__device__ __forceinline__ unsigned mapf(float f) {
  unsigned u = __float_as_uint(f);
  return (u & 0x80000000u) ? ~u : (u | 0x80000000u);
}
__device__ __forceinline__ float unmapf(unsigned u) {
  return __uint_as_float((u & 0x80000000u) ? (u & 0x7FFFFFFFu) : ~u);
}

__global__ void fill_att_k(unsigned* __restrict__ smax, float* __restrict__ denom, int n)
{
  int i = blockIdx.x * 256 + threadIdx.x;
  if (i < n) { smax[i] = 0x007FFFFFu; denom[i] = 0.f; }  // mapf(-inf)
}

__global__ void edge_max_k(const int* __restrict__ es, const int* __restrict__ ed,
                           const int* __restrict__ et, const float4* __restrict__ as_,
                           const float4* __restrict__ ad_, unsigned* __restrict__ smax,
                           int E, int j)
{
  int e = blockIdx.x * 256 + threadIdx.x;
  if (e >= E || et[e] != j) return;
  int s = es[e], d = ed[e];
  float4 a = as_[s], b = ad_[d];
  float v[4] = {a.x + b.x, a.y + b.y, a.z + b.z, a.w + b.w};
#pragma unroll
  for (int hh = 0; hh < 4; hh++) {
    float sc = v[hh] > 0.f ? v[hh] : 0.2f * v[hh];
    atomicMax(smax + d * 4 + hh, mapf(sc));
  }
}

__global__ void edge_sum_k(const int* __restrict__ es, const int* __restrict__ ed,
                           const int* __restrict__ et, const float4* __restrict__ as_,
                           const float4* __restrict__ ad_, const unsigned* __restrict__ smax,
                           float* __restrict__ denom, float4* __restrict__ exbuf, int E, int j)
{
  int e = blockIdx.x * 256 + threadIdx.x;
  if (e >= E || et[e] != j) return;
  int s = es[e], d = ed[e];
  float4 a = as_[s], b = ad_[d];
  float v[4] = {a.x + b.x, a.y + b.y, a.z + b.z, a.w + b.w};
  float ex[4];
#pragma unroll
  for (int hh = 0; hh < 4; hh++) {
    float sc = v[hh] > 0.f ? v[hh] : 0.2f * v[hh];
    float m = unmapf(smax[d * 4 + hh]);
    ex[hh] = expf(sc - m);
    atomicAdd(denom + d * 4 + hh, ex[hh]);
  }
  exbuf[e] = make_float4(ex[0], ex[1], ex[2], ex[3]);
}

// grid = E blocks x 64 threads; out[d] += alpha * h[s]
__global__ void edge_agg_k(const int* __restrict__ es, const int* __restrict__ ed,
                           const int* __restrict__ et, const float* __restrict__ exbuf,
                           const float* __restrict__ denom, const bf16* __restrict__ h,
                           float* __restrict__ out, int j)
{
  int e = blockIdx.x;
  if (et[e] != j) return;
  int l = threadIdx.x;
  int s = es[e], d = ed[e];
  int head = l >> 4;
  float alpha = exbuf[e * 4 + head] / fmaxf(denom[d * 4 + head], 1e-16f);
  const bf16x8 hv = *(const bf16x8*)(h + (size_t)s * HID + l * 8);
  float* o = out + (size_t)d * HID + l * 8;
#pragma unroll
  for (int t = 0; t < 8; t++)
    atomicAdd(o + t, alpha * (float)hv[t]);
}

// bias_out[c] = bsk[c] + sum_{j<R} brel[j*512+c]
__global__ void bias_combine_k(const float* __restrict__ bsk, const float* __restrict__ brel,
                               float* __restrict__ out, int R)
{
  int c = blockIdx.x * 256 + threadIdx.x;
  if (c >= HID) return;
  float v = bsk[c];
  for (int j = 0; j < R; j++) v += brel[j * HID + c];
  out[c] = v;
}

__global__ void fill_f32_k(float* __restrict__ p, float v, int n)
{
  int i = blockIdx.x * 256 + threadIdx.x;
  if (i < n) p[i] = v;
}

// column sums/sumsq of (X + bias) over `rows` rows; 256 threads, thread t -> cols 2t,2t+1
__global__ void bn_stats_k(const float* __restrict__ X, const float* __restrict__ bias,
                           float* __restrict__ sums, float* __restrict__ sumsq, int rows)
{
  int t = threadIdx.x;
  int c0 = t * 2;
  float b0 = bias[c0], b1 = bias[c0 + 1];
  float s0 = 0, s1 = 0, q0 = 0, q1 = 0;
  for (int r = blockIdx.x; r < rows; r += gridDim.x) {
    float2 v = *(const float2*)(X + (size_t)r * HID + c0);
    float v0 = v.x + b0, v1 = v.y + b1;
    s0 += v0; q0 += v0 * v0;
    s1 += v1; q1 += v1 * v1;
  }
  atomicAdd(sums + c0, s0); atomicAdd(sums + c0 + 1, s1);
  atomicAdd(sumsq + c0, q0); atomicAdd(sumsq + c0 + 1, q1);
}

// ACT 0 = ELU, 1 = ReLU. Writes bf16, pad rows (>=rows, <rowsPad) zeroed.
template <int ACT>
__global__ void bn_apply_k(const float* __restrict__ X, const float* __restrict__ bias,
                           const float* __restrict__ sums, const float* __restrict__ sumsq,
                           const float* __restrict__ gamma, const float* __restrict__ beta,
                           bf16* __restrict__ Y, int rows, float invN)
{
  int idx = blockIdx.x * 256 + threadIdx.x;
  int row = idx >> 9, c = idx & 511;
  float y = 0.f;
  if (row < rows) {
    float mu = sums[c] * invN;
    float var = sumsq[c] * invN - mu * mu;
    float v = X[idx] + bias[c];
    float xn = (v - mu) * rsqrtf(var + 1e-5f);
    y = gamma[c] * xn + beta[c];
    y = (ACT == 0) ? (y > 0.f ? y : expm1f(y)) : fmaxf(y, 0.f);
  }
  Y[idx] = (bf16)y;
}

// ---------------------------------------------------------------------------
extern "C" void kernel_launch(void* const* d_in, const int* in_sizes, int n_in,
                              void* d_out, int out_size, void* d_ws, size_t ws_size,
                              hipStream_t stream)
{
  const float* x    = (const float*)d_in[0];
  const int*   es0  = (const int*)d_in[1];
  const int*   ed0  = (const int*)d_in[2];
  const int*   et0  = (const int*)d_in[3];
  const int*   es1  = (const int*)d_in[4];
  const int*   ed1  = (const int*)d_in[5];
  const int*   et1  = (const int*)d_in[6];
  const float* W0   = (const float*)d_in[7];
  const float* as0  = (const float*)d_in[8];
  const float* ad0  = (const float*)d_in[9];
  const float* b0   = (const float*)d_in[10];
  const float* Wsk0 = (const float*)d_in[11];
  const float* bsk0 = (const float*)d_in[12];
  const float* g0   = (const float*)d_in[13];
  const float* be0  = (const float*)d_in[14];
  const float* W1   = (const float*)d_in[15];
  const float* as1  = (const float*)d_in[16];
  const float* ad1  = (const float*)d_in[17];
  const float* b1   = (const float*)d_in[18];
  const float* Wsk1 = (const float*)d_in[19];
  const float* bsk1 = (const float*)d_in[20];
  const float* g1   = (const float*)d_in[21];
  const float* be1  = (const float*)d_in[22];
  const float* Wm1  = (const float*)d_in[23];
  const float* bm1  = (const float*)d_in[24];
  const float* gm   = (const float*)d_in[25];
  const float* bmn  = (const float*)d_in[26];
  const float* Wm2  = (const float*)d_in[27];
  const float* bm2  = (const float*)d_in[28];

  // workspace carve
  char* wsb = (char*)d_ws;
  size_t off = 0;
  auto alloc = [&](size_t bytes) -> char* {
    char* p = wsb + off;
    off = (off + bytes + 255) & ~(size_t)255;
    return p;
  };
  bf16*  xb     = (bf16*)alloc((size_t)M0P * K0 * 2);
  bf16*  hbuf   = (bf16*)alloc((size_t)M0P * HID * 2);
  bf16*  h1b    = (bf16*)alloc((size_t)N1P * HID * 2);
  bf16*  h2b    = (bf16*)alloc((size_t)N2P * HID * 2);
  bf16*  zbb    = (bf16*)alloc((size_t)N2P * HID * 2);
  float* out0   = (float*)alloc((size_t)N1P * HID * 4);
  float* out1   = (float*)alloc((size_t)N2P * HID * 4);
  float* zf     = (float*)alloc((size_t)N2P * HID * 4);
  bf16*  W0t    = (bf16*)alloc((size_t)NREL * HID * K0 * 2);
  bf16*  Wsk0t  = (bf16*)alloc((size_t)HID * K0 * 2);
  bf16*  W1t    = (bf16*)alloc((size_t)NREL * HID * HID * 2);
  bf16*  Wsk1t  = (bf16*)alloc((size_t)HID * HID * 2);
  bf16*  Wm1t   = (bf16*)alloc((size_t)HID * HID * 2);
  bf16*  Wm2t   = (bf16*)alloc((size_t)OUTP * HID * 2);
  float* asb    = (float*)alloc((size_t)M0 * 4 * 4);
  float* adb    = (float*)alloc((size_t)N1 * 4 * 4);
  unsigned* smaxb = (unsigned*)alloc((size_t)N1 * 4 * 4);
  float* denomb = (float*)alloc((size_t)N1 * 4 * 4);
  float* exb    = (float*)alloc((size_t)E0 * 4 * 4);
  float* biasb  = (float*)alloc(HID * 4);
  float* statsb = (float*)alloc(1024 * 4);

  auto gemm = [&](int mode, const bf16* A, const bf16* Bt, void* C, int Mpad, int N,
                  int K, int Mv, int Nv, int ldc, const float* bias) {
    dim3 g(Mpad / 128, N / 128);
    if (mode == 0)
      gemm_bt<0><<<g, 256, 0, stream>>>(A, Bt, C, N, K, 0, 0, 0, nullptr);
    else if (mode == 1)
      gemm_bt<1><<<g, 256, 0, stream>>>(A, Bt, C, N, K, 0, 0, 0, nullptr);
    else
      gemm_bt<2><<<g, 256, 0, stream>>>(A, Bt, C, N, K, Mv, Nv, ldc, bias);
  };

  auto relations = [&](const bf16* xin, int Msrc, int MsrcPad, int Kin, const bf16* Wt,
                       const float* a_src, const float* a_dst, const int* es, const int* ed,
                       const int* et, int E, int ndst, float* outacc) {
    for (int j = 0; j < NREL; j++) {
      gemm(0, xin, Wt + (size_t)j * HID * Kin, hbuf, MsrcPad, HID, Kin, 0, 0, 0, nullptr);
      scores_k<<<Msrc, 64, 0, stream>>>(hbuf, a_src + j * HID, a_dst + j * HID, asb, adb, ndst);
      fill_att_k<<<(ndst * 4 + 255) / 256, 256, 0, stream>>>(smaxb, denomb, ndst * 4);
      edge_max_k<<<(E + 255) / 256, 256, 0, stream>>>(es, ed, et, (const float4*)asb,
                                                      (const float4*)adb, smaxb, E, j);
      edge_sum_k<<<(E + 255) / 256, 256, 0, stream>>>(es, ed, et, (const float4*)asb,
                                                      (const float4*)adb, smaxb, denomb,
                                                      (float4*)exb, E, j);
      edge_agg_k<<<E, 64, 0, stream>>>(es, ed, et, exb, denomb, hbuf, outacc, j);
    }
  };

  // ---- input conversions ----
  cast_pad_k<<<((size_t)M0P * K0 / 8 + 255) / 256, 256, 0, stream>>>(
      x, xb, (long)M0 * K0, (long)M0P * K0);
  for (int j = 0; j < NREL; j++)
    transpose_cast_k<<<dim3(3, 512), 256, 0, stream>>>(
        W0 + (size_t)j * K0 * HID, W0t + (size_t)j * HID * K0, K0, HID, HID);
  transpose_cast_k<<<dim3(3, 512), 256, 0, stream>>>(Wsk0, Wsk0t, K0, HID, HID);
  for (int j = 0; j < NREL; j++)
    transpose_cast_k<<<dim3(2, 512), 256, 0, stream>>>(
        W1 + (size_t)j * HID * HID, W1t + (size_t)j * HID * HID, HID, HID, HID);
  transpose_cast_k<<<dim3(2, 512), 256, 0, stream>>>(Wsk1, Wsk1t, HID, HID, HID);
  transpose_cast_k<<<dim3(2, 512), 256, 0, stream>>>(Wm1, Wm1t, HID, HID, HID);
  transpose_cast_k<<<dim3(2, OUTP), 256, 0, stream>>>(Wm2, Wm2t, HID, OUTC, OUTC);

  // ---- layer 0 ----
  gemm(1, xb, Wsk0t, out0, N1P, HID, K0, 0, 0, 0, nullptr);  // skip into accumulator
  relations(xb, M0, M0P, K0, W0t, as0, ad0, es0, ed0, et0, E0, N1, out0);
  bias_combine_k<<<2, 256, 0, stream>>>(bsk0, b0, biasb, NREL);
  fill_f32_k<<<4, 256, 0, stream>>>(statsb, 0.f, 1024);
  bn_stats_k<<<256, 256, 0, stream>>>(out0, biasb, statsb, statsb + 512, N1);
  bn_apply_k<0><<<(N1P * HID) / 256, 256, 0, stream>>>(out0, biasb, statsb, statsb + 512,
                                                       g0, be0, h1b, N1, 1.f / N1);

  // ---- layer 1 ----
  gemm(1, h1b, Wsk1t, out1, N2P, HID, HID, 0, 0, 0, nullptr);
  relations(h1b, N1, N1P, HID, W1t, as1, ad1, es1, ed1, et1, E1, N2, out1);
  bias_combine_k<<<2, 256, 0, stream>>>(bsk1, b1, biasb, NREL);
  fill_f32_k<<<4, 256, 0, stream>>>(statsb, 0.f, 1024);
  bn_stats_k<<<256, 256, 0, stream>>>(out1, biasb, statsb, statsb + 512, N2);
  bn_apply_k<0><<<(N2P * HID) / 256, 256, 0, stream>>>(out1, biasb, statsb, statsb + 512,
                                                       g1, be1, h2b, N2, 1.f / N2);

  // ---- MLP head ----
  gemm(1, h2b, Wm1t, zf, N2P, HID, HID, 0, 0, 0, nullptr);
  fill_f32_k<<<4, 256, 0, stream>>>(statsb, 0.f, 1024);
  bn_stats_k<<<256, 256, 0, stream>>>(zf, bm1, statsb, statsb + 512, N2);
  bn_apply_k<1><<<(N2P * HID) / 256, 256, 0, stream>>>(zf, bm1, statsb, statsb + 512,
                                                       gm, bmn, zbb, N2, 1.f / N2);
  gemm(2, zbb, Wm2t, d_out, N2P, OUTP, HID, N2, OUTC, OUTC, bm2);

  (void)in_sizes; (void)n_in; (void)out_size; (void)ws_size;
}

// Round 2
// 2462.330 us; speedup vs baseline: 5.1702x; 5.1702x over previous
//
#include <hip/hip_runtime.h>
#include <math.h>

typedef __bf16 bf16;
typedef __bf16 bf16x8 __attribute__((ext_vector_type(8)));
typedef float f32x4 __attribute__((ext_vector_type(4)));

#define M0   120000
#define M0P  120064   // 938*128
#define K0   768
#define HID  512
#define NREL 5
#define N1   30000
#define N1P  30080    // 235*128
#define E0   600000
#define N2   8000
#define N2P  8064     // 63*128
#define E1   150000
#define OUTC 153
#define OUTP 256

#define GLOAD_LDS16(g, s) \
  __builtin_amdgcn_global_load_lds((const __attribute__((address_space(1))) void*)(g), \
                                   (__attribute__((address_space(3))) void*)(s), 16, 0, 0)

// ---------------------------------------------------------------------------
// GEMM: C[M x N] = A[M x K](bf16, row-major) * Bt[N x K](bf16, row-major)^T
// 128x128 tile, 4 waves of 64x64, mfma_f32_16x16x32_bf16, global_load_lds(16B)
// MODE 0: store bf16, ldc=N. MODE 1: store f32, ldc=N. MODE 2: f32+bias, guarded.
// ---------------------------------------------------------------------------
template <int MODE>
__global__ __launch_bounds__(256) void gemm_bt(
    const bf16* __restrict__ A, const bf16* __restrict__ Bt, void* __restrict__ Cout,
    int N, int K, int Mv, int Nv, int ldc, const float* __restrict__ bias)
{
  __shared__ __attribute__((aligned(16))) bf16 As[128 * 32];
  __shared__ __attribute__((aligned(16))) bf16 Bs[128 * 32];
  const int tid = threadIdx.x;
  const int w = tid >> 6, l = tid & 63;
  const int tm = blockIdx.x * 128, tn = blockIdx.y * 128;
  const int wm = (w >> 1) * 64, wn = (w & 1) * 64;
  const int lr = l & 15, q = l >> 4;

  f32x4 acc[4][4] = {};

  const int arow = l >> 2;
  const int acol = (l & 3) * 8;
  const bf16* Ag = A + (size_t)tm * K + acol;
  const bf16* Bg = Bt + (size_t)tn * K + acol;

  for (int k0 = 0; k0 < K; k0 += 32) {
#pragma unroll
    for (int i = 0; i < 2; i++) {
      int rb = __builtin_amdgcn_readfirstlane(16 * (2 * w + i));
      GLOAD_LDS16(Ag + (size_t)(rb + arow) * K + k0, As + rb * 32);
      GLOAD_LDS16(Bg + (size_t)(rb + arow) * K + k0, Bs + rb * 32);
    }
    __syncthreads();
    bf16x8 af[4], bfr[4];
#pragma unroll
    for (int i = 0; i < 4; i++)
      af[i] = *(const bf16x8*)&As[(wm + i * 16 + lr) * 32 + q * 8];
#pragma unroll
    for (int jj = 0; jj < 4; jj++)
      bfr[jj] = *(const bf16x8*)&Bs[(wn + jj * 16 + lr) * 32 + q * 8];
#pragma unroll
    for (int i = 0; i < 4; i++)
#pragma unroll
      for (int jj = 0; jj < 4; jj++)
        acc[i][jj] = __builtin_amdgcn_mfma_f32_16x16x32_bf16(af[i], bfr[jj], acc[i][jj], 0, 0, 0);
    __syncthreads();
  }

  // C/D layout (m89-verified): col = lane&15, row = (lane>>4)*4 + reg
#pragma unroll
  for (int i = 0; i < 4; i++)
#pragma unroll
    for (int jj = 0; jj < 4; jj++)
#pragma unroll
      for (int r = 0; r < 4; r++) {
        int row = tm + wm + i * 16 + q * 4 + r;
        int col = tn + wn + jj * 16 + lr;
        float v = acc[i][jj][r];
        if (MODE == 0) {
          ((bf16*)Cout)[(size_t)row * N + col] = (bf16)v;
        } else if (MODE == 1) {
          ((float*)Cout)[(size_t)row * N + col] = v;
        } else {
          if (row < Mv && col < Nv)
            ((float*)Cout)[(size_t)row * ldc + col] = v + bias[col];
        }
      }
}

// ---------------------------------------------------------------------------
__global__ void cast_pad_k(const float* __restrict__ src, bf16* __restrict__ dst,
                           long nvalid, long ntot)
{
  long i = ((long)blockIdx.x * 256 + threadIdx.x) * 8;
  if (i >= ntot) return;
  bf16x8 o;
  if (i + 8 <= nvalid) {
    float4 v0 = *(const float4*)(src + i);
    float4 v1 = *(const float4*)(src + i + 4);
    o[0] = (bf16)v0.x; o[1] = (bf16)v0.y; o[2] = (bf16)v0.z; o[3] = (bf16)v0.w;
    o[4] = (bf16)v1.x; o[5] = (bf16)v1.y; o[6] = (bf16)v1.z; o[7] = (bf16)v1.w;
  } else {
#pragma unroll
    for (int t = 0; t < 8; t++)
      o[t] = (i + t < nvalid) ? (bf16)src[i + t] : (bf16)0.f;
  }
  *(bf16x8*)(dst + i) = o;
}

__global__ void transpose_cast_k(const float* __restrict__ W, bf16* __restrict__ Wt,
                                 int K, int Nsrc, int Nvalid)
{
  int n = blockIdx.y;
  int k = blockIdx.x * 256 + threadIdx.x;
  Wt[(size_t)n * K + k] = (n < Nvalid) ? (bf16)W[(size_t)k * Nsrc + n] : (bf16)0.f;
}

// ---------------------------------------------------------------------------
// attention score projections
// ---------------------------------------------------------------------------
__global__ void scores_k(const bf16* __restrict__ h, const float* __restrict__ asj,
                         const float* __restrict__ adj, float* __restrict__ as_out,
                         float* __restrict__ ad_out, int ndst)
{
  int n = blockIdx.x;
  int l = threadIdx.x;
  const bf16x8 hv = *(const bf16x8*)(h + (size_t)n * HID + l * 8);
  int head = l >> 4;
  int base = head * 128 + (l & 15) * 8;
  float ps = 0.f, pd = 0.f;
#pragma unroll
  for (int t = 0; t < 8; t++) {
    float hx = (float)hv[t];
    ps += hx * asj[base + t];
    pd += hx * adj[base + t];
  }
#pragma unroll
  for (int o = 8; o > 0; o >>= 1) {
    ps += __shfl_down(ps, o, 16);
    pd += __shfl_down(pd, o, 16);
  }
  if ((l & 15) == 0) {
    as_out[n * 4 + head] = ps;
    if (n < ndst) ad_out[n * 4 + head] = pd;
  }
}

// ---------------------------------------------------------------------------
// CSR build: counting sort of edges keyed by (type, dst)
// ---------------------------------------------------------------------------
__global__ void fill_i32_k(int* __restrict__ p, int v, int n)
{
  int i = blockIdx.x * 256 + threadIdx.x;
  if (i < n) p[i] = v;
}

__global__ void hist_k(const int* __restrict__ et, const int* __restrict__ ed,
                       int* __restrict__ cnt, int E, int ndst)
{
  int e = blockIdx.x * 256 + threadIdx.x;
  if (e >= E) return;
  atomicAdd(&cnt[et[e] * ndst + ed[e]], 1);
}

// per-256-block exclusive scan; block totals to bsums
__global__ void scan1_k(const int* __restrict__ in, int* __restrict__ out,
                        int* __restrict__ bsums, int n)
{
  __shared__ int sh[256];
  int t = threadIdx.x;
  int i = blockIdx.x * 256 + t;
  int v = (i < n) ? in[i] : 0;
  sh[t] = v;
  __syncthreads();
#pragma unroll
  for (int o = 1; o < 256; o <<= 1) {
    int x = 0;
    if (t >= o) x = sh[t - o];
    __syncthreads();
    if (t >= o) sh[t] += x;
    __syncthreads();
  }
  if (i < n) out[i] = sh[t] - v;
  if (t == 255) bsums[blockIdx.x] = sh[255];
}

// single-block exclusive scan over n <= 1024 block sums (in place)
__global__ void scan2_k(int* __restrict__ b, int n)
{
  __shared__ int sh[1024];
  int t = threadIdx.x;
  int v = (t < n) ? b[t] : 0;
  sh[t] = v;
  __syncthreads();
#pragma unroll
  for (int o = 1; o < 1024; o <<= 1) {
    int x = 0;
    if (t >= o) x = sh[t - o];
    __syncthreads();
    if (t >= o) sh[t] += x;
    __syncthreads();
  }
  if (t < n) b[t] = sh[t] - v;
}

__global__ void add_off_k(int* __restrict__ out, const int* __restrict__ bscan, int n)
{
  int i = blockIdx.x * 256 + threadIdx.x;
  if (i < n) out[i] += bscan[blockIdx.x];
}

// cursor = copy of offsets; also writes the end sentinel offsets[nkeys] = E
__global__ void copy_cursor_k(int* __restrict__ off, int* __restrict__ cur, int n, int E)
{
  int i = blockIdx.x * 256 + threadIdx.x;
  if (i < n) cur[i] = off[i];
  if (i == 0) off[n] = E;
}

// stores SOURCE NODE id (not edge id) at the sorted position
__global__ void scatter_k(const int* __restrict__ es, const int* __restrict__ ed,
                          const int* __restrict__ et, int* __restrict__ cur,
                          int* __restrict__ sorted_src, int E, int ndst)
{
  int e = blockIdx.x * 256 + threadIdx.x;
  if (e >= E) return;
  int pos = atomicAdd(&cur[et[e] * ndst + ed[e]], 1);
  sorted_src[pos] = es[e];
}

// ---------------------------------------------------------------------------
// fused per-destination softmax + aggregate. grid = ndst blocks x 64 threads.
// off points at offsets + j*ndst. out[d] += sum_e alpha_e * h[src_e].
// ---------------------------------------------------------------------------
__global__ void agg_csr_k(const int* __restrict__ sorted_src, const int* __restrict__ off,
                          const float4* __restrict__ as_, const float4* __restrict__ ad_,
                          const bf16* __restrict__ h, float* __restrict__ out)
{
  int d = blockIdx.x, l = threadIdx.x;
  int beg = off[d], end = off[d + 1];
  if (beg == end) return;
  int head = l >> 4;
  float4 bd = ad_[d];

  // pass 1: per-head max of leaky-relu scores
  float m[4] = {-INFINITY, -INFINITY, -INFINITY, -INFINITY};
  for (int p = beg; p < end; p++) {
    int s = sorted_src[p];
    float4 a = as_[s];
    float v[4] = {a.x + bd.x, a.y + bd.y, a.z + bd.z, a.w + bd.w};
#pragma unroll
    for (int hh = 0; hh < 4; hh++) {
      float sc = v[hh] > 0.f ? v[hh] : 0.2f * v[hh];
      m[hh] = fmaxf(m[hh], sc);
    }
  }

  // pass 2: unnormalized sum of exp * h, plus denominator
  float den[4] = {0.f, 0.f, 0.f, 0.f};
  float acc[8] = {0.f, 0.f, 0.f, 0.f, 0.f, 0.f, 0.f, 0.f};
  for (int p = beg; p < end; p++) {
    int s = sorted_src[p];
    float4 a = as_[s];
    float v[4] = {a.x + bd.x, a.y + bd.y, a.z + bd.z, a.w + bd.w};
    float ex[4];
#pragma unroll
    for (int hh = 0; hh < 4; hh++) {
      float sc = v[hh] > 0.f ? v[hh] : 0.2f * v[hh];
      ex[hh] = __expf(sc - m[hh]);
      den[hh] += ex[hh];
    }
    float wgt = ex[head];
    const bf16x8 hv = *(const bf16x8*)(h + (size_t)s * HID + l * 8);
#pragma unroll
    for (int t = 0; t < 8; t++)
      acc[t] += wgt * (float)hv[t];
  }

  float scale = 1.f / fmaxf(den[head], 1e-16f);
  float* o = out + (size_t)d * HID + l * 8;
#pragma unroll
  for (int t = 0; t < 8; t++)
    o[t] += acc[t] * scale;
}

// ---------------------------------------------------------------------------
__global__ void bias_combine_k(const float* __restrict__ bsk, const float* __restrict__ brel,
                               float* __restrict__ out, int R)
{
  int c = blockIdx.x * 256 + threadIdx.x;
  if (c >= HID) return;
  float v = bsk[c];
  for (int j = 0; j < R; j++) v += brel[j * HID + c];
  out[c] = v;
}

__global__ void fill_f32_k(float* __restrict__ p, float v, int n)
{
  int i = blockIdx.x * 256 + threadIdx.x;
  if (i < n) p[i] = v;
}

__global__ void bn_stats_k(const float* __restrict__ X, const float* __restrict__ bias,
                           float* __restrict__ sums, float* __restrict__ sumsq, int rows)
{
  int t = threadIdx.x;
  int c0 = t * 2;
  float b0 = bias[c0], b1 = bias[c0 + 1];
  float s0 = 0, s1 = 0, q0 = 0, q1 = 0;
  for (int r = blockIdx.x; r < rows; r += gridDim.x) {
    float2 v = *(const float2*)(X + (size_t)r * HID + c0);
    float v0 = v.x + b0, v1 = v.y + b1;
    s0 += v0; q0 += v0 * v0;
    s1 += v1; q1 += v1 * v1;
  }
  atomicAdd(sums + c0, s0); atomicAdd(sums + c0 + 1, s1);
  atomicAdd(sumsq + c0, q0); atomicAdd(sumsq + c0 + 1, q1);
}

template <int ACT>
__global__ void bn_apply_k(const float* __restrict__ X, const float* __restrict__ bias,
                           const float* __restrict__ sums, const float* __restrict__ sumsq,
                           const float* __restrict__ gamma, const float* __restrict__ beta,
                           bf16* __restrict__ Y, int rows, float invN)
{
  int idx = blockIdx.x * 256 + threadIdx.x;
  int row = idx >> 9, c = idx & 511;
  float y = 0.f;
  if (row < rows) {
    float mu = sums[c] * invN;
    float var = sumsq[c] * invN - mu * mu;
    float v = X[idx] + bias[c];
    float xn = (v - mu) * rsqrtf(var + 1e-5f);
    y = gamma[c] * xn + beta[c];
    y = (ACT == 0) ? (y > 0.f ? y : expm1f(y)) : fmaxf(y, 0.f);
  }
  Y[idx] = (bf16)y;
}

// ---------------------------------------------------------------------------
extern "C" void kernel_launch(void* const* d_in, const int* in_sizes, int n_in,
                              void* d_out, int out_size, void* d_ws, size_t ws_size,
                              hipStream_t stream)
{
  const float* x    = (const float*)d_in[0];
  const int*   es0  = (const int*)d_in[1];
  const int*   ed0  = (const int*)d_in[2];
  const int*   et0  = (const int*)d_in[3];
  const int*   es1  = (const int*)d_in[4];
  const int*   ed1  = (const int*)d_in[5];
  const int*   et1  = (const int*)d_in[6];
  const float* W0   = (const float*)d_in[7];
  const float* as0  = (const float*)d_in[8];
  const float* ad0  = (const float*)d_in[9];
  const float* b0   = (const float*)d_in[10];
  const float* Wsk0 = (const float*)d_in[11];
  const float* bsk0 = (const float*)d_in[12];
  const float* g0   = (const float*)d_in[13];
  const float* be0  = (const float*)d_in[14];
  const float* W1   = (const float*)d_in[15];
  const float* as1  = (const float*)d_in[16];
  const float* ad1  = (const float*)d_in[17];
  const float* b1   = (const float*)d_in[18];
  const float* Wsk1 = (const float*)d_in[19];
  const float* bsk1 = (const float*)d_in[20];
  const float* g1   = (const float*)d_in[21];
  const float* be1  = (const float*)d_in[22];
  const float* Wm1  = (const float*)d_in[23];
  const float* bm1  = (const float*)d_in[24];
  const float* gm   = (const float*)d_in[25];
  const float* bmn  = (const float*)d_in[26];
  const float* Wm2  = (const float*)d_in[27];
  const float* bm2  = (const float*)d_in[28];

  char* wsb = (char*)d_ws;
  size_t off = 0;
  auto alloc = [&](size_t bytes) -> char* {
    char* p = wsb + off;
    off = (off + bytes + 255) & ~(size_t)255;
    return p;
  };
  bf16*  xb     = (bf16*)alloc((size_t)M0P * K0 * 2);
  bf16*  hbuf   = (bf16*)alloc((size_t)M0P * HID * 2);
  bf16*  h1b    = (bf16*)alloc((size_t)N1P * HID * 2);
  bf16*  h2b    = (bf16*)alloc((size_t)N2P * HID * 2);
  bf16*  zbb    = (bf16*)alloc((size_t)N2P * HID * 2);
  float* out0   = (float*)alloc((size_t)N1P * HID * 4);
  float* out1   = (float*)alloc((size_t)N2P * HID * 4);
  float* zf     = (float*)alloc((size_t)N2P * HID * 4);
  bf16*  W0t    = (bf16*)alloc((size_t)NREL * HID * K0 * 2);
  bf16*  Wsk0t  = (bf16*)alloc((size_t)HID * K0 * 2);
  bf16*  W1t    = (bf16*)alloc((size_t)NREL * HID * HID * 2);
  bf16*  Wsk1t  = (bf16*)alloc((size_t)HID * HID * 2);
  bf16*  Wm1t   = (bf16*)alloc((size_t)HID * HID * 2);
  bf16*  Wm2t   = (bf16*)alloc((size_t)OUTP * HID * 2);
  float* asb    = (float*)alloc((size_t)M0 * 4 * 4);
  float* adb    = (float*)alloc((size_t)N1 * 4 * 4);
  float* biasb  = (float*)alloc(HID * 4);
  float* statsb = (float*)alloc(1024 * 4);
  // CSR buffers (sized for layer 0, reused for layer 1)
  int* offb   = (int*)alloc((size_t)(NREL * N1 + 1) * 4);  // offsets + sentinel
  int* curb   = (int*)alloc((size_t)(NREL * N1) * 4);      // histogram, then cursor
  int* bsumsb = (int*)alloc(1024 * 4);
  int* srtb   = (int*)alloc((size_t)E0 * 4);               // sorted source ids

  auto gemm = [&](int mode, const bf16* A, const bf16* Bt, void* C, int Mpad, int N,
                  int K, int Mv, int Nv, int ldc, const float* bias) {
    dim3 g(Mpad / 128, N / 128);
    if (mode == 0)
      gemm_bt<0><<<g, 256, 0, stream>>>(A, Bt, C, N, K, 0, 0, 0, nullptr);
    else if (mode == 1)
      gemm_bt<1><<<g, 256, 0, stream>>>(A, Bt, C, N, K, 0, 0, 0, nullptr);
    else
      gemm_bt<2><<<g, 256, 0, stream>>>(A, Bt, C, N, K, Mv, Nv, ldc, bias);
  };

  auto build_csr = [&](const int* es, const int* ed, const int* et, int E, int ndst) {
    int nkeys = NREL * ndst;
    int nbE = (E + 255) / 256;
    int nbK = (nkeys + 255) / 256;
    fill_i32_k<<<nbK, 256, 0, stream>>>(curb, 0, nkeys);
    hist_k<<<nbE, 256, 0, stream>>>(et, ed, curb, E, ndst);
    scan1_k<<<nbK, 256, 0, stream>>>(curb, offb, bsumsb, nkeys);
    scan2_k<<<1, 1024, 0, stream>>>(bsumsb, nbK);
    add_off_k<<<nbK, 256, 0, stream>>>(offb, bsumsb, nkeys);
    copy_cursor_k<<<nbK, 256, 0, stream>>>(offb, curb, nkeys, E);
    scatter_k<<<nbE, 256, 0, stream>>>(es, ed, et, curb, srtb, E, ndst);
  };

  auto relations = [&](const bf16* xin, int Msrc, int MsrcPad, int Kin, const bf16* Wt,
                       const float* a_src, const float* a_dst, int ndst, float* outacc) {
    for (int j = 0; j < NREL; j++) {
      gemm(0, xin, Wt + (size_t)j * HID * Kin, hbuf, MsrcPad, HID, Kin, 0, 0, 0, nullptr);
      scores_k<<<Msrc, 64, 0, stream>>>(hbuf, a_src + j * HID, a_dst + j * HID, asb, adb, ndst);
      agg_csr_k<<<ndst, 64, 0, stream>>>(srtb, offb + j * ndst, (const float4*)asb,
                                         (const float4*)adb, hbuf, outacc);
    }
  };

  // ---- input conversions ----
  cast_pad_k<<<((size_t)M0P * K0 / 8 + 255) / 256, 256, 0, stream>>>(
      x, xb, (long)M0 * K0, (long)M0P * K0);
  for (int j = 0; j < NREL; j++)
    transpose_cast_k<<<dim3(3, 512), 256, 0, stream>>>(
        W0 + (size_t)j * K0 * HID, W0t + (size_t)j * HID * K0, K0, HID, HID);
  transpose_cast_k<<<dim3(3, 512), 256, 0, stream>>>(Wsk0, Wsk0t, K0, HID, HID);
  for (int j = 0; j < NREL; j++)
    transpose_cast_k<<<dim3(2, 512), 256, 0, stream>>>(
        W1 + (size_t)j * HID * HID, W1t + (size_t)j * HID * HID, HID, HID, HID);
  transpose_cast_k<<<dim3(2, 512), 256, 0, stream>>>(Wsk1, Wsk1t, HID, HID, HID);
  transpose_cast_k<<<dim3(2, 512), 256, 0, stream>>>(Wm1, Wm1t, HID, HID, HID);
  transpose_cast_k<<<dim3(2, OUTP), 256, 0, stream>>>(Wm2, Wm2t, HID, OUTC, OUTC);

  // ---- layer 0 ----
  build_csr(es0, ed0, et0, E0, N1);
  gemm(1, xb, Wsk0t, out0, N1P, HID, K0, 0, 0, 0, nullptr);  // skip into accumulator
  relations(xb, M0, M0P, K0, W0t, as0, ad0, N1, out0);
  bias_combine_k<<<2, 256, 0, stream>>>(bsk0, b0, biasb, NREL);
  fill_f32_k<<<4, 256, 0, stream>>>(statsb, 0.f, 1024);
  bn_stats_k<<<256, 256, 0, stream>>>(out0, biasb, statsb, statsb + 512, N1);
  bn_apply_k<0><<<(N1P * HID) / 256, 256, 0, stream>>>(out0, biasb, statsb, statsb + 512,
                                                       g0, be0, h1b, N1, 1.f / N1);

  // ---- layer 1 ----
  build_csr(es1, ed1, et1, E1, N2);
  gemm(1, h1b, Wsk1t, out1, N2P, HID, HID, 0, 0, 0, nullptr);
  relations(h1b, N1, N1P, HID, W1t, as1, ad1, N2, out1);
  bias_combine_k<<<2, 256, 0, stream>>>(bsk1, b1, biasb, NREL);
  fill_f32_k<<<4, 256, 0, stream>>>(statsb, 0.f, 1024);
  bn_stats_k<<<256, 256, 0, stream>>>(out1, biasb, statsb, statsb + 512, N2);
  bn_apply_k<0><<<(N2P * HID) / 256, 256, 0, stream>>>(out1, biasb, statsb, statsb + 512,
                                                       g1, be1, h2b, N2, 1.f / N2);

  // ---- MLP head ----
  gemm(1, h2b, Wm1t, zf, N2P, HID, HID, 0, 0, 0, nullptr);
  fill_f32_k<<<4, 256, 0, stream>>>(statsb, 0.f, 1024);
  bn_stats_k<<<256, 256, 0, stream>>>(zf, bm1, statsb, statsb + 512, N2);
  bn_apply_k<1><<<(N2P * HID) / 256, 256, 0, stream>>>(zf, bm1, statsb, statsb + 512,
                                                       gm, bmn, zbb, N2, 1.f / N2);
  gemm(2, zbb, Wm2t, d_out, N2P, OUTP, HID, N2, OUTC, OUTC, bm2);

  (void)in_sizes; (void)n_in; (void)out_size; (void)ws_size;
}

// Round 3
// 2140.195 us; speedup vs baseline: 5.9484x; 1.1505x over previous
//
#include <hip/hip_runtime.h>
#include <math.h>

typedef __bf16 bf16;
typedef __bf16 bf16x4 __attribute__((ext_vector_type(4)));
typedef __bf16 bf16x8 __attribute__((ext_vector_type(8)));
typedef float f32x4 __attribute__((ext_vector_type(4)));

#define M0   120000
#define M0P  120064   // 938*128
#define K0   768
#define HID  512
#define NREL 5
#define N1   30000
#define N1P  30080    // 235*128
#define E0   600000
#define N2   8000
#define N2P  8064     // 63*128
#define E1   150000
#define OUTC 153
#define OUTP 256

#define GLOAD_LDS16(g, s) \
  __builtin_amdgcn_global_load_lds((const __attribute__((address_space(1))) void*)(g), \
                                   (__attribute__((address_space(3))) void*)(s), 16, 0, 0)

// ---------------------------------------------------------------------------
// GEMM: C[M x N] = A[M x K](bf16 rm) * Bt[N x K](bf16 rm)^T
// MODE 1: store f32, ldc=N. MODE 2: f32+bias, guarded, ldc param.
// ---------------------------------------------------------------------------
template <int MODE>
__global__ __launch_bounds__(256) void gemm_bt(
    const bf16* __restrict__ A, const bf16* __restrict__ Bt, void* __restrict__ Cout,
    int N, int K, int Mv, int Nv, int ldc, const float* __restrict__ bias)
{
  __shared__ __attribute__((aligned(16))) bf16 As[128 * 32];
  __shared__ __attribute__((aligned(16))) bf16 Bs[128 * 32];
  const int tid = threadIdx.x;
  const int w = tid >> 6, l = tid & 63;
  const int tm = blockIdx.x * 128, tn = blockIdx.y * 128;
  const int wm = (w >> 1) * 64, wn = (w & 1) * 64;
  const int lr = l & 15, q = l >> 4;

  f32x4 acc[4][4] = {};

  const int arow = l >> 2;
  const int acol = (l & 3) * 8;
  const bf16* Ag = A + (size_t)tm * K + acol;
  const bf16* Bg = Bt + (size_t)tn * K + acol;

  for (int k0 = 0; k0 < K; k0 += 32) {
#pragma unroll
    for (int i = 0; i < 2; i++) {
      int rb = __builtin_amdgcn_readfirstlane(16 * (2 * w + i));
      GLOAD_LDS16(Ag + (size_t)(rb + arow) * K + k0, As + rb * 32);
      GLOAD_LDS16(Bg + (size_t)(rb + arow) * K + k0, Bs + rb * 32);
    }
    __syncthreads();
    bf16x8 af[4], bfr[4];
#pragma unroll
    for (int i = 0; i < 4; i++)
      af[i] = *(const bf16x8*)&As[(wm + i * 16 + lr) * 32 + q * 8];
#pragma unroll
    for (int jj = 0; jj < 4; jj++)
      bfr[jj] = *(const bf16x8*)&Bs[(wn + jj * 16 + lr) * 32 + q * 8];
#pragma unroll
    for (int i = 0; i < 4; i++)
#pragma unroll
      for (int jj = 0; jj < 4; jj++)
        acc[i][jj] = __builtin_amdgcn_mfma_f32_16x16x32_bf16(af[i], bfr[jj], acc[i][jj], 0, 0, 0);
    __syncthreads();
  }

#pragma unroll
  for (int i = 0; i < 4; i++)
#pragma unroll
    for (int jj = 0; jj < 4; jj++)
#pragma unroll
      for (int r = 0; r < 4; r++) {
        int row = tm + wm + i * 16 + q * 4 + r;
        int col = tn + wn + jj * 16 + lr;
        float v = acc[i][jj][r];
        if (MODE == 1) {
          ((float*)Cout)[(size_t)row * N + col] = v;
        } else {
          if (row < Mv && col < Nv)
            ((float*)Cout)[(size_t)row * ldc + col] = v + bias[col];
        }
      }
}

// ---------------------------------------------------------------------------
// batched head-recombination GEMM: for z in [0,4): C[., z*128 + c] += A_z @ B_z^T
// A_z = A0 + z*sA : [M x K] bf16; B_z = B0 + z*sB : [128 x K] bf16; C f32 ldc=512
// ---------------------------------------------------------------------------
__global__ __launch_bounds__(256) void gemm_recomb(
    const bf16* __restrict__ A0, size_t sA, const bf16* __restrict__ B0, size_t sB,
    float* __restrict__ C, int K)
{
  __shared__ __attribute__((aligned(16))) bf16 As[128 * 32];
  __shared__ __attribute__((aligned(16))) bf16 Bs[128 * 32];
  const bf16* A = A0 + blockIdx.z * sA;
  const bf16* Bt = B0 + blockIdx.z * sB;
  const int tid = threadIdx.x;
  const int w = tid >> 6, l = tid & 63;
  const int tm = blockIdx.x * 128;
  const int wm = (w >> 1) * 64, wn = (w & 1) * 64;
  const int lr = l & 15, q = l >> 4;

  f32x4 acc[4][4] = {};
  const int arow = l >> 2;
  const int acol = (l & 3) * 8;
  const bf16* Ag = A + (size_t)tm * K + acol;
  const bf16* Bg = Bt + acol;

  for (int k0 = 0; k0 < K; k0 += 32) {
#pragma unroll
    for (int i = 0; i < 2; i++) {
      int rb = __builtin_amdgcn_readfirstlane(16 * (2 * w + i));
      GLOAD_LDS16(Ag + (size_t)(rb + arow) * K + k0, As + rb * 32);
      GLOAD_LDS16(Bg + (size_t)(rb + arow) * K + k0, Bs + rb * 32);
    }
    __syncthreads();
    bf16x8 af[4], bfr[4];
#pragma unroll
    for (int i = 0; i < 4; i++)
      af[i] = *(const bf16x8*)&As[(wm + i * 16 + lr) * 32 + q * 8];
#pragma unroll
    for (int jj = 0; jj < 4; jj++)
      bfr[jj] = *(const bf16x8*)&Bs[(wn + jj * 16 + lr) * 32 + q * 8];
#pragma unroll
    for (int i = 0; i < 4; i++)
#pragma unroll
      for (int jj = 0; jj < 4; jj++)
        acc[i][jj] = __builtin_amdgcn_mfma_f32_16x16x32_bf16(af[i], bfr[jj], acc[i][jj], 0, 0, 0);
    __syncthreads();
  }

#pragma unroll
  for (int i = 0; i < 4; i++)
#pragma unroll
    for (int jj = 0; jj < 4; jj++)
#pragma unroll
      for (int r = 0; r < 4; r++) {
        int row = tm + wm + i * 16 + q * 4 + r;
        int col = blockIdx.z * 128 + wn + jj * 16 + lr;
        C[(size_t)row * 512 + col] += acc[i][jj][r];
      }
}

// ---------------------------------------------------------------------------
__global__ void cast_pad_k(const float* __restrict__ src, bf16* __restrict__ dst,
                           long nvalid, long ntot)
{
  long i = ((long)blockIdx.x * 256 + threadIdx.x) * 8;
  if (i >= ntot) return;
  bf16x8 o;
  if (i + 8 <= nvalid) {
    float4 v0 = *(const float4*)(src + i);
    float4 v1 = *(const float4*)(src + i + 4);
    o[0] = (bf16)v0.x; o[1] = (bf16)v0.y; o[2] = (bf16)v0.z; o[3] = (bf16)v0.w;
    o[4] = (bf16)v1.x; o[5] = (bf16)v1.y; o[6] = (bf16)v1.z; o[7] = (bf16)v1.w;
  } else {
#pragma unroll
    for (int t = 0; t < 8; t++)
      o[t] = (i + t < nvalid) ? (bf16)src[i + t] : (bf16)0.f;
  }
  *(bf16x8*)(dst + i) = o;
}

__global__ void transpose_cast_k(const float* __restrict__ W, bf16* __restrict__ Wt,
                                 int K, int Nsrc, int Nvalid)
{
  int n = blockIdx.y;
  int k = blockIdx.x * 256 + threadIdx.x;
  Wt[(size_t)n * K + k] = (n < Nvalid) ? (bf16)W[(size_t)k * Nsrc + n] : (bf16)0.f;
}

// Brec[h][c][j*K+k] = Wt[j*512 + h*128 + c][k]; flat i = ((h*128+c)*NREL + j)*K + k
__global__ void reorder_brec_k(const bf16* __restrict__ Wt, bf16* __restrict__ Brec, int K)
{
  int i = blockIdx.x * 256 + threadIdx.x;
  int k = i % K;
  int rest = i / K;
  int j = rest % NREL;
  int rest2 = rest / NREL;
  int c = rest2 & 127;
  int h = rest2 >> 7;
  Brec[i] = Wt[((size_t)(j * 512 + h * 128 + c)) * K + k];
}

// wvec[col][k] = sum_c W[j][k][h*128+c] * a[j][h][c]; col = j*8 + side*4 + h (<40)
__global__ void wvec_k(const float* __restrict__ W, const float* __restrict__ a_s,
                       const float* __restrict__ a_d, bf16* __restrict__ wv, int K)
{
  int k = blockIdx.x * 64 + threadIdx.x;
  int col = blockIdx.y;
  float v = 0.f;
  if (col < 40) {
    int j = col >> 3, side = (col >> 2) & 1, h = col & 3;
    const float* Wrow = W + ((size_t)j * K + k) * 512 + h * 128;
    const float* av = (side ? a_d : a_s) + (j * 4 + h) * 128;
    for (int c = 0; c < 128; c++) v += Wrow[c] * av[c];
  }
  wv[(size_t)col * K + k] = (bf16)v;
}

// ---------------------------------------------------------------------------
// CSR build
// ---------------------------------------------------------------------------
__global__ void fill_i32_k(int* __restrict__ p, int v, int n)
{
  int i = blockIdx.x * 256 + threadIdx.x;
  if (i < n) p[i] = v;
}

__global__ void hist_k(const int* __restrict__ et, const int* __restrict__ ed,
                       int* __restrict__ cnt, int E, int ndst)
{
  int e = blockIdx.x * 256 + threadIdx.x;
  if (e >= E) return;
  atomicAdd(&cnt[et[e] * ndst + ed[e]], 1);
}

__global__ void scan1_k(const int* __restrict__ in, int* __restrict__ out,
                        int* __restrict__ bsums, int n)
{
  __shared__ int sh[256];
  int t = threadIdx.x;
  int i = blockIdx.x * 256 + t;
  int v = (i < n) ? in[i] : 0;
  sh[t] = v;
  __syncthreads();
#pragma unroll
  for (int o = 1; o < 256; o <<= 1) {
    int x = 0;
    if (t >= o) x = sh[t - o];
    __syncthreads();
    if (t >= o) sh[t] += x;
    __syncthreads();
  }
  if (i < n) out[i] = sh[t] - v;
  if (t == 255) bsums[blockIdx.x] = sh[255];
}

__global__ void scan2_k(int* __restrict__ b, int n)
{
  __shared__ int sh[1024];
  int t = threadIdx.x;
  int v = (t < n) ? b[t] : 0;
  sh[t] = v;
  __syncthreads();
#pragma unroll
  for (int o = 1; o < 1024; o <<= 1) {
    int x = 0;
    if (t >= o) x = sh[t - o];
    __syncthreads();
    if (t >= o) sh[t] += x;
    __syncthreads();
  }
  if (t < n) b[t] = sh[t] - v;
}

__global__ void add_off_k(int* __restrict__ out, const int* __restrict__ bscan, int n)
{
  int i = blockIdx.x * 256 + threadIdx.x;
  if (i < n) out[i] += bscan[blockIdx.x];
}

__global__ void copy_cursor_k(int* __restrict__ off, int* __restrict__ cur, int n, int E)
{
  int i = blockIdx.x * 256 + threadIdx.x;
  if (i < n) cur[i] = off[i];
  if (i == 0) off[n] = E;
}

__global__ void scatter_k(const int* __restrict__ es, const int* __restrict__ ed,
                          const int* __restrict__ et, int* __restrict__ cur,
                          int* __restrict__ sorted_src, int E, int ndst)
{
  int e = blockIdx.x * 256 + threadIdx.x;
  if (e >= E) return;
  int pos = atomicAdd(&cur[et[e] * ndst + ed[e]], 1);
  sorted_src[pos] = es[e];
}

// ---------------------------------------------------------------------------
// x-space softmax-aggregate. grid = (ndst, NREL) x 64 threads.
// aggx[h][d][j*K + k] = sum_e alpha[e,h] * X[src_e][k]  (bf16 out, f32 acc)
// scoresbuf [.][128]: col j*8+h = a_s, col j*8+4+h = a_d
// ---------------------------------------------------------------------------
template <int K, int CH>   // CH = K/256  (bf16x4 chunks per lane)
__global__ void agg_x_k(const int* __restrict__ sorted_src, const int* __restrict__ off,
                        const float* __restrict__ scoresbuf, const bf16* __restrict__ X,
                        bf16* __restrict__ aggx, int ndst, int nrows)
{
  int d = blockIdx.x, j = blockIdx.y, l = threadIdx.x;
  int key = j * ndst + d;
  int beg = off[key], end = off[key + 1];
  float4 svd = *(const float4*)(scoresbuf + (size_t)d * 128 + j * 8 + 4);

  float m[4] = {-INFINITY, -INFINITY, -INFINITY, -INFINITY};
  for (int p = beg; p < end; p++) {
    int s = sorted_src[p];
    float4 sv = *(const float4*)(scoresbuf + (size_t)s * 128 + j * 8);
    float v[4] = {sv.x + svd.x, sv.y + svd.y, sv.z + svd.z, sv.w + svd.w};
#pragma unroll
    for (int h = 0; h < 4; h++) {
      float sc = v[h] > 0.f ? v[h] : 0.2f * v[h];
      m[h] = fmaxf(m[h], sc);
    }
  }

  int myh = l & 3;
  float den[4] = {0.f, 0.f, 0.f, 0.f};
  float acc[4][CH * 4] = {};
  for (int p = beg; p < end; p++) {
    int s = sorted_src[p];
    float4 sv = *(const float4*)(scoresbuf + (size_t)s * 128 + j * 8);
    float v[4] = {sv.x + svd.x, sv.y + svd.y, sv.z + svd.z, sv.w + svd.w};
    float scm = v[myh] > 0.f ? v[myh] : 0.2f * v[myh];
    float e = __expf(scm - m[myh]);
    float ex[4];
#pragma unroll
    for (int h = 0; h < 4; h++) {
      ex[h] = __shfl(e, (l & 60) | h);
      den[h] += ex[h];
    }
    const bf16* xr = X + (size_t)s * K + l * (CH * 4);
#pragma unroll
    for (int c = 0; c < CH; c++) {
      bf16x4 xv = *(const bf16x4*)(xr + c * 4);
#pragma unroll
      for (int t = 0; t < 4; t++) {
        float f = (float)xv[t];
#pragma unroll
        for (int h = 0; h < 4; h++)
          acc[h][c * 4 + t] += ex[h] * f;
      }
    }
  }

#pragma unroll
  for (int h = 0; h < 4; h++) {
    float sc = 1.f / fmaxf(den[h], 1e-16f);
    bf16* orow = aggx + ((size_t)h * nrows + d) * ((size_t)NREL * K) + (size_t)j * K + l * (CH * 4);
#pragma unroll
    for (int c = 0; c < CH; c++) {
      bf16x4 o;
#pragma unroll
      for (int t = 0; t < 4; t++) o[t] = (bf16)(acc[h][c * 4 + t] * sc);
      *(bf16x4*)(orow + c * 4) = o;
    }
  }
}

// ---------------------------------------------------------------------------
__global__ void bias_combine_k(const float* __restrict__ bsk, const float* __restrict__ brel,
                               float* __restrict__ out, int R)
{
  int c = blockIdx.x * 256 + threadIdx.x;
  if (c >= HID) return;
  float v = bsk[c];
  for (int j = 0; j < R; j++) v += brel[j * HID + c];
  out[c] = v;
}

__global__ void fill_f32_k(float* __restrict__ p, float v, int n)
{
  int i = blockIdx.x * 256 + threadIdx.x;
  if (i < n) p[i] = v;
}

__global__ void bn_stats_k(const float* __restrict__ X, const float* __restrict__ bias,
                           float* __restrict__ sums, float* __restrict__ sumsq, int rows)
{
  int t = threadIdx.x;
  int c0 = t * 2;
  float b0 = bias[c0], b1 = bias[c0 + 1];
  float s0 = 0, s1 = 0, q0 = 0, q1 = 0;
  for (int r = blockIdx.x; r < rows; r += gridDim.x) {
    float2 v = *(const float2*)(X + (size_t)r * HID + c0);
    float v0 = v.x + b0, v1 = v.y + b1;
    s0 += v0; q0 += v0 * v0;
    s1 += v1; q1 += v1 * v1;
  }
  atomicAdd(sums + c0, s0); atomicAdd(sums + c0 + 1, s1);
  atomicAdd(sumsq + c0, q0); atomicAdd(sumsq + c0 + 1, q1);
}

template <int ACT>
__global__ void bn_apply_k(const float* __restrict__ X, const float* __restrict__ bias,
                           const float* __restrict__ sums, const float* __restrict__ sumsq,
                           const float* __restrict__ gamma, const float* __restrict__ beta,
                           bf16* __restrict__ Y, int rows, float invN)
{
  int idx = blockIdx.x * 256 + threadIdx.x;
  int row = idx >> 9, c = idx & 511;
  float y = 0.f;
  if (row < rows) {
    float mu = sums[c] * invN;
    float var = sumsq[c] * invN - mu * mu;
    float v = X[idx] + bias[c];
    float xn = (v - mu) * rsqrtf(var + 1e-5f);
    y = gamma[c] * xn + beta[c];
    y = (ACT == 0) ? (y > 0.f ? y : expm1f(y)) : fmaxf(y, 0.f);
  }
  Y[idx] = (bf16)y;
}

// ---------------------------------------------------------------------------
extern "C" void kernel_launch(void* const* d_in, const int* in_sizes, int n_in,
                              void* d_out, int out_size, void* d_ws, size_t ws_size,
                              hipStream_t stream)
{
  const float* x    = (const float*)d_in[0];
  const int*   es0  = (const int*)d_in[1];
  const int*   ed0  = (const int*)d_in[2];
  const int*   et0  = (const int*)d_in[3];
  const int*   es1  = (const int*)d_in[4];
  const int*   ed1  = (const int*)d_in[5];
  const int*   et1  = (const int*)d_in[6];
  const float* W0   = (const float*)d_in[7];
  const float* as0  = (const float*)d_in[8];
  const float* ad0  = (const float*)d_in[9];
  const float* b0   = (const float*)d_in[10];
  const float* Wsk0 = (const float*)d_in[11];
  const float* bsk0 = (const float*)d_in[12];
  const float* g0   = (const float*)d_in[13];
  const float* be0  = (const float*)d_in[14];
  const float* W1   = (const float*)d_in[15];
  const float* as1  = (const float*)d_in[16];
  const float* ad1  = (const float*)d_in[17];
  const float* b1   = (const float*)d_in[18];
  const float* Wsk1 = (const float*)d_in[19];
  const float* bsk1 = (const float*)d_in[20];
  const float* g1   = (const float*)d_in[21];
  const float* be1  = (const float*)d_in[22];
  const float* Wm1  = (const float*)d_in[23];
  const float* bm1  = (const float*)d_in[24];
  const float* gm   = (const float*)d_in[25];
  const float* bmn  = (const float*)d_in[26];
  const float* Wm2  = (const float*)d_in[27];
  const float* bm2  = (const float*)d_in[28];

  char* wsb = (char*)d_ws;
  size_t off = 0;
  auto alloc = [&](size_t bytes) -> char* {
    char* p = wsb + off;
    off = (off + bytes + 255) & ~(size_t)255;
    return p;
  };
  // persistent / small
  bf16*  Wsk0t  = (bf16*)alloc((size_t)HID * K0 * 2);
  bf16*  Wsk1t  = (bf16*)alloc((size_t)HID * HID * 2);
  bf16*  Wm1t   = (bf16*)alloc((size_t)HID * HID * 2);
  bf16*  Wm2t   = (bf16*)alloc((size_t)OUTP * HID * 2);
  bf16*  W0t    = (bf16*)alloc((size_t)NREL * HID * K0 * 2);
  bf16*  W1t    = (bf16*)alloc((size_t)NREL * HID * HID * 2);
  bf16*  Brec0  = (bf16*)alloc((size_t)4 * 128 * NREL * K0 * 2);
  bf16*  Brec1  = (bf16*)alloc((size_t)4 * 128 * NREL * HID * 2);
  bf16*  wvec0  = (bf16*)alloc((size_t)128 * K0 * 2);
  bf16*  wvec1  = (bf16*)alloc((size_t)128 * HID * 2);
  float* biasb  = (float*)alloc(HID * 4);
  float* statsb = (float*)alloc(1024 * 4);
  int*   offb   = (int*)alloc((size_t)(NREL * N1 + 1) * 4);
  int*   curb   = (int*)alloc((size_t)NREL * N1 * 4);
  int*   bsumsb = (int*)alloc(1024 * 4);
  int*   srtb   = (int*)alloc((size_t)E0 * 4);
  float* out0   = (float*)alloc((size_t)N1P * HID * 4);
  bf16*  h1b    = (bf16*)alloc((size_t)N1P * HID * 2);
  bf16*  h2b    = (bf16*)alloc((size_t)N2P * HID * 2);
  bf16*  zbb    = (bf16*)alloc((size_t)N2P * HID * 2);
  float* out1   = (float*)alloc((size_t)N2P * HID * 4);
  float* zf     = (float*)alloc((size_t)N2P * HID * 4);
  // big regions
  bf16*  xb        = (bf16*)alloc((size_t)M0P * K0 * 2);
  float* scoresbuf = (float*)alloc((size_t)M0P * 128 * 4);
  bf16*  aggx      = (bf16*)alloc((size_t)4 * N1P * NREL * K0 * 2);  // reused for layer 1

  auto build_csr = [&](const int* es, const int* ed, const int* et, int E, int ndst) {
    int nkeys = NREL * ndst;
    int nbE = (E + 255) / 256;
    int nbK = (nkeys + 255) / 256;
    fill_i32_k<<<nbK, 256, 0, stream>>>(curb, 0, nkeys);
    hist_k<<<nbE, 256, 0, stream>>>(et, ed, curb, E, ndst);
    scan1_k<<<nbK, 256, 0, stream>>>(curb, offb, bsumsb, nkeys);
    scan2_k<<<1, 1024, 0, stream>>>(bsumsb, nbK);
    add_off_k<<<nbK, 256, 0, stream>>>(offb, bsumsb, nkeys);
    copy_cursor_k<<<nbK, 256, 0, stream>>>(offb, curb, nkeys, E);
    scatter_k<<<nbE, 256, 0, stream>>>(es, ed, et, curb, srtb, E, ndst);
  };

  // ---- weight prep ----
  cast_pad_k<<<((size_t)M0P * K0 / 8 + 255) / 256, 256, 0, stream>>>(
      x, xb, (long)M0 * K0, (long)M0P * K0);
  for (int j = 0; j < NREL; j++)
    transpose_cast_k<<<dim3(3, 512), 256, 0, stream>>>(
        W0 + (size_t)j * K0 * HID, W0t + (size_t)j * HID * K0, K0, HID, HID);
  transpose_cast_k<<<dim3(3, 512), 256, 0, stream>>>(Wsk0, Wsk0t, K0, HID, HID);
  for (int j = 0; j < NREL; j++)
    transpose_cast_k<<<dim3(2, 512), 256, 0, stream>>>(
        W1 + (size_t)j * HID * HID, W1t + (size_t)j * HID * HID, HID, HID, HID);
  transpose_cast_k<<<dim3(2, 512), 256, 0, stream>>>(Wsk1, Wsk1t, HID, HID, HID);
  transpose_cast_k<<<dim3(2, 512), 256, 0, stream>>>(Wm1, Wm1t, HID, HID, HID);
  transpose_cast_k<<<dim3(2, OUTP), 256, 0, stream>>>(Wm2, Wm2t, HID, OUTC, OUTC);
  reorder_brec_k<<<(4 * 128 * NREL * K0) / 256, 256, 0, stream>>>(W0t, Brec0, K0);
  reorder_brec_k<<<(4 * 128 * NREL * HID) / 256, 256, 0, stream>>>(W1t, Brec1, HID);
  wvec_k<<<dim3(K0 / 64, 128), 64, 0, stream>>>(W0, as0, ad0, wvec0, K0);
  wvec_k<<<dim3(HID / 64, 128), 64, 0, stream>>>(W1, as1, ad1, wvec1, HID);

  // ---- layer 0 ----
  {
    const int KT = NREL * K0;  // 3840
    build_csr(es0, ed0, et0, E0, N1);
    gemm_bt<1><<<dim3(M0P / 128, 1), 256, 0, stream>>>(xb, wvec0, scoresbuf, 128, K0, 0, 0, 0, nullptr);
    gemm_bt<1><<<dim3(N1P / 128, 4), 256, 0, stream>>>(xb, Wsk0t, out0, HID, K0, 0, 0, 0, nullptr);
    // zero pad rows of aggx (d in [N1, N1P))
    for (int h = 0; h < 4; h++)
      fill_i32_k<<<((N1P - N1) * KT * 2 / 4 + 255) / 256, 256, 0, stream>>>(
          (int*)(aggx + ((size_t)h * N1P + N1) * KT), 0, (N1P - N1) * KT / 2);
    agg_x_k<K0, K0 / 256><<<dim3(N1, NREL), 64, 0, stream>>>(
        srtb, offb, scoresbuf, xb, aggx, N1, N1P);
    gemm_recomb<<<dim3(N1P / 128, 1, 4), 256, 0, stream>>>(
        aggx, (size_t)N1P * KT, Brec0, (size_t)128 * KT, out0, KT);
    bias_combine_k<<<2, 256, 0, stream>>>(bsk0, b0, biasb, NREL);
    fill_f32_k<<<4, 256, 0, stream>>>(statsb, 0.f, 1024);
    bn_stats_k<<<256, 256, 0, stream>>>(out0, biasb, statsb, statsb + 512, N1);
    bn_apply_k<0><<<(N1P * HID) / 256, 256, 0, stream>>>(out0, biasb, statsb, statsb + 512,
                                                         g0, be0, h1b, N1, 1.f / N1);
  }

  // ---- layer 1 ----
  {
    const int KT = NREL * HID;  // 2560
    build_csr(es1, ed1, et1, E1, N2);
    gemm_bt<1><<<dim3(N1P / 128, 1), 256, 0, stream>>>(h1b, wvec1, scoresbuf, 128, HID, 0, 0, 0, nullptr);
    gemm_bt<1><<<dim3(N2P / 128, 4), 256, 0, stream>>>(h1b, Wsk1t, out1, HID, HID, 0, 0, 0, nullptr);
    for (int h = 0; h < 4; h++)
      fill_i32_k<<<((N2P - N2) * KT * 2 / 4 + 255) / 256, 256, 0, stream>>>(
          (int*)(aggx + ((size_t)h * N2P + N2) * KT), 0, (N2P - N2) * KT / 2);
    agg_x_k<HID, HID / 256><<<dim3(N2, NREL), 64, 0, stream>>>(
        srtb, offb, scoresbuf, h1b, aggx, N2, N2P);
    gemm_recomb<<<dim3(N2P / 128, 1, 4), 256, 0, stream>>>(
        aggx, (size_t)N2P * KT, Brec1, (size_t)128 * KT, out1, KT);
    bias_combine_k<<<2, 256, 0, stream>>>(bsk1, b1, biasb, NREL);
    fill_f32_k<<<4, 256, 0, stream>>>(statsb, 0.f, 1024);
    bn_stats_k<<<256, 256, 0, stream>>>(out1, biasb, statsb, statsb + 512, N2);
    bn_apply_k<0><<<(N2P * HID) / 256, 256, 0, stream>>>(out1, biasb, statsb, statsb + 512,
                                                         g1, be1, h2b, N2, 1.f / N2);
  }

  // ---- MLP head ----
  gemm_bt<1><<<dim3(N2P / 128, 4), 256, 0, stream>>>(h2b, Wm1t, zf, HID, HID, 0, 0, 0, nullptr);
  fill_f32_k<<<4, 256, 0, stream>>>(statsb, 0.f, 1024);
  bn_stats_k<<<256, 256, 0, stream>>>(zf, bm1, statsb, statsb + 512, N2);
  bn_apply_k<1><<<(N2P * HID) / 256, 256, 0, stream>>>(zf, bm1, statsb, statsb + 512,
                                                       gm, bmn, zbb, N2, 1.f / N2);
  gemm_bt<2><<<dim3(N2P / 128, OUTP / 128), 256, 0, stream>>>(
      zbb, Wm2t, d_out, OUTP, HID, N2, OUTC, OUTC, bm2);

  (void)in_sizes; (void)n_in; (void)out_size; (void)ws_size;
}